// Round 3
// baseline (292.200 us; speedup 1.0000x reference)
//
#include <hip/hip_runtime.h>

// GraphNN collapsed to exact affine form:
//   out = (x @ Mo + co) / n_out; norms from G = x^T x, s = colsum(x):
//   n^2 = sum_{w,w'} G[w][w']*H[w][w'] + c-terms,  H = Tt Tt^T.
// Round 14: single-block mega-chain. R2 showed the 4 chain kernels + gaps
// ~ 130us (and grid.sync costs ~50us each -> cooperative fusion is out).
// The chain's real work is ~13us of MFMA on one CU, so: run levels 1..4 +
// final norm in ONE 256-thread block, T-slots ping-ponging between two LDS
// groups (8 slots hi+lo = 144KB), all relays in LDS, only __syncthreads().
// kG / kGred / kApply are EXACTLY the R0-227us versions. 4 dispatches.

#define BF 262144.0f
#define SLOT 4608           // 64*72 u16 per matrix slot

// ws float offsets
#define OFF_G   0
#define OFF_S   4096
#define OFF_MO  91392       // 4096
#define OFF_CO  95488       // 64
#define OFF_X16 98304       // bf16 x copy: 16.78M u16 = 33.6 MB

typedef __attribute__((ext_vector_type(8))) short bf16x8;   // 8 bf16 = 4 VGPRs
typedef __attribute__((ext_vector_type(4))) float f32x4;
typedef __attribute__((ext_vector_type(4))) unsigned short u16x4;

__device__ __forceinline__ unsigned short f2bf(float f) {
  unsigned u = __builtin_bit_cast(unsigned, f);
  u += 0x7FFF + ((u >> 16) & 1);          // round-to-nearest-even
  return (unsigned short)(u >> 16);
}
__device__ __forceinline__ float bf2f(unsigned short h) {
  unsigned u = ((unsigned)h) << 16;
  return __builtin_bit_cast(float, u);
}

__device__ __forceinline__ bf16x8 cvt8(f32x4 a, f32x4 b, float s) {
  bf16x8 t;
#pragma unroll
  for (int j = 0; j < 4; j++) {
    t[j]     = (short)f2bf(a[j] * s);
    t[j + 4] = (short)f2bf(b[j] * s);
  }
  return t;
}

// split 8 floats (scaled) into hi/lo bf16x8
__device__ __forceinline__ void split8(f32x4 a, f32x4 b, float sc,
                                       bf16x8& hi, bf16x8& lo) {
#pragma unroll
  for (int j = 0; j < 4; j++) {
    float v = a[j] * sc;
    unsigned short h = f2bf(v);
    hi[j] = (short)h; lo[j] = (short)f2bf(v - bf2f(h));
    v = b[j] * sc;
    h = f2bf(v);
    hi[j + 4] = (short)h; lo[j + 4] = (short)f2bf(v - bf2f(h));
  }
}

// q MFMA part: sum_{w,w'} G[w][w'] * (Tt Tt^T)[w][w'] for one T-slot
__device__ __forceinline__ float qpart(const unsigned short* th,
                                       const unsigned short* tl,
                                       int it, int col, int quad,
                                       const float Greg[4][4]) {
  f32x4 dq[4];
#pragma unroll
  for (int ut = 0; ut < 4; ut++) dq[ut] = (f32x4){0.f, 0.f, 0.f, 0.f};
#pragma unroll
  for (int ks = 0; ks < 2; ks++) {
    const bf16x8 ah = *(const bf16x8*)&th[(it * 16 + col) * 72 + ks * 32 + quad * 8];
    const bf16x8 al = *(const bf16x8*)&tl[(it * 16 + col) * 72 + ks * 32 + quad * 8];
#pragma unroll
    for (int ut = 0; ut < 4; ut++) {
      const bf16x8 bh = *(const bf16x8*)&th[(ut * 16 + col) * 72 + ks * 32 + quad * 8];
      const bf16x8 bl = *(const bf16x8*)&tl[(ut * 16 + col) * 72 + ks * 32 + quad * 8];
      dq[ut] = __builtin_amdgcn_mfma_f32_16x16x32_bf16(ah, bh, dq[ut], 0, 0, 0);
      dq[ut] = __builtin_amdgcn_mfma_f32_16x16x32_bf16(ah, bl, dq[ut], 0, 0, 0);
      dq[ut] = __builtin_amdgcn_mfma_f32_16x16x32_bf16(al, bh, dq[ut], 0, 0, 0);
    }
  }
  float qp = 0.f;
#pragma unroll
  for (int ut = 0; ut < 4; ut++)
#pragma unroll
    for (int r = 0; r < 4; r++) qp += dq[ut][r] * Greg[ut][r];
  return qp;
}

// block reduction of qp -> qvv[idx] = 1/sqrt(sum); uniform control flow
__device__ __forceinline__ void blkred(float qp, float* red4, float* qvv,
                                       int idx, int tid, int lane, int it) {
#pragma unroll
  for (int off = 32; off; off >>= 1) qp += __shfl_down(qp, off, 64);
  if (lane == 0) red4[it] = qp;
  __syncthreads();
  if (tid == 0) qvv[idx] = 1.0f / sqrtf(red4[0] + red4[1] + red4[2] + red4[3]);
  __syncthreads();
}

// q-phase over 4 slots of one group -> qvv[0..3]
__device__ __forceinline__ void qphase(const unsigned short* th0,
                                       const unsigned short* tl0,
                                       const float* cX, const float Greg[4][4],
                                       const float* slv, float* red4, float* qvv,
                                       int tid, int lane, int it, int col, int quad) {
#pragma unroll
  for (int n = 0; n < 4; n++) {
    float qp = qpart(th0 + n * SLOT, tl0 + n * SLOT, it, col, quad, Greg);
    if (tid < 64) {
      float sd = 0.f;
      for (int w = 0; w < 64; w++)
        sd += slv[w] * (bf2f(th0[n * SLOT + w * 72 + tid]) +
                        bf2f(tl0[n * SLOT + w * 72 + tid]));
      const float c = cX[n * 64 + tid];
      qp += c * (2.f * sd + BF * c);
    }
    blkred(qp, red4, qvv, n, tid, lane, it);
  }
}

// level compose: dst_tgt = sum_src inv_src * (W[src][tgt] @ src_slot);
// cDst[tgt] = sum_src (inv_src * W[src][tgt] @ cSrc[src] + b[src][tgt]).
__device__ __forceinline__ void compose(const unsigned short* sTh, const unsigned short* sTl,
                                        unsigned short* dTh, unsigned short* dTl,
                                        const float* cSrc, float* cDst,
                                        const float* Wl, const float* bl,
                                        const float* qvv,
                                        int tid, int lane, int it, int col, int quad) {
  const int arow = it * 16 + col;
  f32x4 wr[4];
  {
    const float* wbase = Wl + (long)(0 * 64 + arow) * 64;   // (src=0,tgt=0)
    wr[0] = *(const f32x4*)(wbase + quad * 8);
    wr[1] = *(const f32x4*)(wbase + quad * 8 + 4);
    wr[2] = *(const f32x4*)(wbase + 32 + quad * 8);
    wr[3] = *(const f32x4*)(wbase + 36 + quad * 8);
  }
  f32x4 dc[4];
#pragma unroll
  for (int nt = 0; nt < 4; nt++) dc[nt] = (f32x4){0.f, 0.f, 0.f, 0.f};
#pragma unroll
  for (int e = 0; e < 16; e++) {
    const int tgt = e >> 2, src = e & 3;
    const float inv = qvv[src];
    bf16x8 awh0, awl0, awh1, awl1;
    split8(wr[0], wr[1], inv, awh0, awl0);
    split8(wr[2], wr[3], inv, awh1, awl1);
    if (e < 15) {   // prefetch next (src',tgt') W rows under the MFMAs
      const int e1 = e + 1, tgt1 = e1 >> 2, src1 = e1 & 3;
      const float* wbase = Wl + (long)((src1 * 4 + tgt1) * 64 + arow) * 64;
      wr[0] = *(const f32x4*)(wbase + quad * 8);
      wr[1] = *(const f32x4*)(wbase + quad * 8 + 4);
      wr[2] = *(const f32x4*)(wbase + 32 + quad * 8);
      wr[3] = *(const f32x4*)(wbase + 36 + quad * 8);
    }
    const unsigned short* bh_ = sTh + src * SLOT;
    const unsigned short* bl_ = sTl + src * SLOT;
#pragma unroll
    for (int nt = 0; nt < 4; nt++) {
      const bf16x8 bh0 = *(const bf16x8*)&bh_[(nt * 16 + col) * 72 + quad * 8];
      const bf16x8 bl0 = *(const bf16x8*)&bl_[(nt * 16 + col) * 72 + quad * 8];
      dc[nt] = __builtin_amdgcn_mfma_f32_16x16x32_bf16(awh0, bh0, dc[nt], 0, 0, 0);
      dc[nt] = __builtin_amdgcn_mfma_f32_16x16x32_bf16(awh0, bl0, dc[nt], 0, 0, 0);
      dc[nt] = __builtin_amdgcn_mfma_f32_16x16x32_bf16(awl0, bh0, dc[nt], 0, 0, 0);
      const bf16x8 bh1 = *(const bf16x8*)&bh_[(nt * 16 + col) * 72 + 32 + quad * 8];
      const bf16x8 bl1 = *(const bf16x8*)&bl_[(nt * 16 + col) * 72 + 32 + quad * 8];
      dc[nt] = __builtin_amdgcn_mfma_f32_16x16x32_bf16(awh1, bh1, dc[nt], 0, 0, 0);
      dc[nt] = __builtin_amdgcn_mfma_f32_16x16x32_bf16(awh1, bl1, dc[nt], 0, 0, 0);
      dc[nt] = __builtin_amdgcn_mfma_f32_16x16x32_bf16(awl1, bh1, dc[nt], 0, 0, 0);
    }
    if (src == 3) {          // tgt complete: write split into dst slot tgt
#pragma unroll
      for (int nt = 0; nt < 4; nt++)
#pragma unroll
        for (int r = 0; r < 4; r++) {
          const float val = dc[nt][r];
          const unsigned short h = f2bf(val);
          const int w_ = nt * 16 + col, v_ = it * 16 + quad * 4 + r;
          dTh[tgt * SLOT + w_ * 72 + v_] = h;
          dTl[tgt * SLOT + w_ * 72 + v_] = f2bf(val - bf2f(h));
        }
#pragma unroll
      for (int nt = 0; nt < 4; nt++) dc[nt] = (f32x4){0.f, 0.f, 0.f, 0.f};
    }
  }
  // c-part: wave `it` produces cDst[it]
  {
    float acc = 0.f;
#pragma unroll
    for (int src = 0; src < 4; src++) {
      const float* wrow = Wl + (long)((src * 4 + it) * 64 + lane) * 64;
      float pc = 0.f;
#pragma unroll
      for (int u4 = 0; u4 < 16; u4++) {
        const f32x4 wv = *(const f32x4*)(wrow + u4 * 4);
        pc += wv[0] * cSrc[src * 64 + u4 * 4]     + wv[1] * cSrc[src * 64 + u4 * 4 + 1] +
              wv[2] * cSrc[src * 64 + u4 * 4 + 2] + wv[3] * cSrc[src * 64 + u4 * 4 + 3];
      }
      acc += qvv[src] * pc + bl[(src * 4 + it) * 64 + lane];
    }
    cDst[it * 64 + lane] = acc;
  }
  __syncthreads();
}

// ---------- kG: partial G = x^T x (bf16 MFMA) + colsum + bf16-x copy --------
// R0 config: 512 blocks x 512 rows, 16 iters.
__global__ __launch_bounds__(256) void kG(const float* __restrict__ x,
                                          float* __restrict__ Gpart,
                                          unsigned short* __restrict__ x16) {
  __shared__ __align__(16) unsigned short xts[4][4][16][8];
  __shared__ float sred[256][4];
  const int tid = threadIdx.x;
  const int lane = tid & 63, mt = tid >> 6;
  const int col = lane & 15, q = lane >> 4;
  const int row0 = tid >> 4;
  const int cf0  = (tid & 15) * 4;

  f32x4 acc[4];
#pragma unroll
  for (int nt = 0; nt < 4; nt++) acc[nt] = (f32x4){0.f, 0.f, 0.f, 0.f};
  float s0 = 0.f, s1 = 0.f, s2 = 0.f, s3 = 0.f;

  const long brow = (long)blockIdx.x * 512;
  const float* bx = x + brow * 64;
  f32x4 r0 = *(const f32x4*)(bx + tid * 4);
  f32x4 r1 = *(const f32x4*)(bx + 1024 + tid * 4);

  for (int c = 0; c < 16; c++) {
    __syncthreads();
    s0 += r0[0] + r1[0]; s1 += r0[1] + r1[1];
    s2 += r0[2] + r1[2]; s3 += r0[3] + r1[3];
    u16x4 h0, h1;
#pragma unroll
    for (int j = 0; j < 4; j++) {
      const int cf = cf0 + j;
      const unsigned short b0 = f2bf(r0[j]);
      const unsigned short b1 = f2bf(r1[j]);
      h0[j] = b0; h1[j] = b1;
      xts[cf >> 4][row0 >> 3][cf & 15][row0 & 7]        = b0;
      xts[cf >> 4][2 + (row0 >> 3)][cf & 15][row0 & 7]  = b1;
    }
    *(u16x4*)(x16 + (brow + c * 32 + row0) * 64 + cf0)      = h0;
    *(u16x4*)(x16 + (brow + c * 32 + 16 + row0) * 64 + cf0) = h1;
    f32x4 r0n = r0, r1n = r1;
    if (c < 15) {
      r0n = *(const f32x4*)(bx + (c + 1) * 2048 + tid * 4);
      r1n = *(const f32x4*)(bx + (c + 1) * 2048 + 1024 + tid * 4);
    }
    __syncthreads();
    const bf16x8 af = *(const bf16x8*)xts[mt][q][col];
#pragma unroll
    for (int nt = 0; nt < 4; nt++) {
      const bf16x8 bfr = *(const bf16x8*)xts[nt][q][col];
      acc[nt] = __builtin_amdgcn_mfma_f32_16x16x32_bf16(af, bfr, acc[nt], 0, 0, 0);
    }
    r0 = r0n; r1 = r1n;
  }

  float* myp = Gpart + (long)blockIdx.x * 4160;
#pragma unroll
  for (int nt = 0; nt < 4; nt++)
#pragma unroll
    for (int r = 0; r < 4; r++)
      myp[(mt * 16 + q * 4 + r) * 64 + nt * 16 + col] = acc[nt][r];

  sred[tid][0] = s0; sred[tid][1] = s1; sred[tid][2] = s2; sred[tid][3] = s3;
  __syncthreads();
  if (tid < 64) {
    float t = 0.f;
#pragma unroll
    for (int k2 = 0; k2 < 16; k2++) t += sred[(tid >> 2) + 16 * k2][tid & 3];
    myp[4096 + tid] = t;
  }
}

// ---------- kGred: reduce 512 partials -> G, s (coalesced) ------------------
__global__ __launch_bounds__(256) void kGred(const float* __restrict__ Gpart,
                                             float* __restrict__ G,
                                             float* __restrict__ s) {
  __shared__ float red[4][64];
  const int tid = threadIdx.x;
  const int e = blockIdx.x * 64 + (tid & 63);
  const int quarter = tid >> 6;
  float acc = 0.f;
#pragma unroll 4
  for (int j = 0; j < 128; j++)
    acc += Gpart[(long)(quarter * 128 + j) * 4160 + e];
  red[quarter][tid & 63] = acc;
  __syncthreads();
  if (tid < 64) {
    const float t = red[0][tid] + red[1][tid] + red[2][tid] + red[3][tid];
    const int ee = blockIdx.x * 64 + tid;
    if (ee < 4096) G[ee] = t;
    else           s[ee - 4096] = t;
  }
}

// ---------- kChain1: entire chain (levels 1..4 + final norm), ONE block -----
__global__ __launch_bounds__(256) void kChain1(
    const float* __restrict__ Win, const float* __restrict__ bin,
    const float* __restrict__ Wmid, const float* __restrict__ bmid,
    const float* __restrict__ Wout, const float* __restrict__ bout,
    const float* __restrict__ G, const float* __restrict__ s,
    float* __restrict__ MoS, float* __restrict__ coS) {
  extern __shared__ __align__(16) char smem[];
  unsigned short* ThA = (unsigned short*)smem;     // 4 slots hi (group A)
  unsigned short* TlA = ThA + 4 * SLOT;            // 4 slots lo
  unsigned short* ThB = TlA + 4 * SLOT;            // 4 slots hi (group B)
  unsigned short* TlB = ThB + 4 * SLOT;            // 4 slots lo
  float* cA   = (float*)(TlB + 4 * SLOT);          // 256
  float* cB   = cA + 256;                          // 256
  float* cF   = cB + 256;                          // 64
  float* slv  = cF + 64;                           // 64
  float* red4 = slv + 64;                          // 4
  float* qvv  = red4 + 4;                          // 8

  const float* Wm0 = Wmid;            const float* bm0 = bmid;
  const float* Wm1 = Wmid + 65536;    const float* bm1 = bmid + 1024;
  const float* Wm2 = Wmid + 131072;   const float* bm2 = bmid + 2048;

  const int tid = threadIdx.x;
  const int lane = tid & 63, it = tid >> 6;
  const int col = lane & 15, quad = lane >> 4;

  float Greg[4][4];
#pragma unroll
  for (int ut = 0; ut < 4; ut++)
#pragma unroll
    for (int r = 0; r < 4; r++)
      Greg[ut][r] = G[(it * 16 + quad * 4 + r) * 64 + ut * 16 + col];
  if (tid < 64) slv[tid] = s[tid];
  cA[tid] = bin[tid];                  // c1[p][v]

  // ---- build T1 slots into group A (Tf f32 staging in group-B region) ----
  {
    float* Tf = (float*)ThB;
    for (int p = 0; p < 4; p++) {
#pragma unroll
      for (int m = 0; m < 4; m++) {
        const int li = m * 1024 + tid * 4;
        *(f32x4*)&Tf[(li >> 6) * 68 + (li & 63)] = *(const f32x4*)(Win + p * 4096 + li);
      }
      __syncthreads();
      const int tc = tid >> 2, rb = (tid & 3) * 16;
#pragma unroll
      for (int j = 0; j < 16; j++) {
        const float tv = Tf[(rb + j) * 68 + tc];
        const unsigned short h = f2bf(tv);
        ThA[p * SLOT + tc * 72 + rb + j] = h;
        TlA[p * SLOT + tc * 72 + rb + j] = f2bf(tv - bf2f(h));
      }
      __syncthreads();
    }
  }

  // ---- level 1 norms ----
  qphase(ThA, TlA, cA, Greg, slv, red4, qvv, tid, lane, it, col, quad);
  // ---- level 2: T2 = f(T1) into group B ----
  compose(ThA, TlA, ThB, TlB, cA, cB, Wm0, bm0, qvv, tid, lane, it, col, quad);
  qphase(ThB, TlB, cB, Greg, slv, red4, qvv, tid, lane, it, col, quad);
  // ---- level 3: T3 into group A ----
  compose(ThB, TlB, ThA, TlA, cB, cA, Wm1, bm1, qvv, tid, lane, it, col, quad);
  qphase(ThA, TlA, cA, Greg, slv, red4, qvv, tid, lane, it, col, quad);
  // ---- level 4: T4 into group B ----
  compose(ThA, TlA, ThB, TlB, cA, cB, Wm2, bm2, qvv, tid, lane, it, col, quad);
  qphase(ThB, TlB, cB, Greg, slv, red4, qvv, tid, lane, it, col, quad);

  // ---- final: TF = sum_k' inv4_k' * (Wout_k' @ T4_k'); norm; write Mo/co ----
  {
    const int arow = it * 16 + col;
    f32x4 dcF[4];
#pragma unroll
    for (int nt = 0; nt < 4; nt++) dcF[nt] = (f32x4){0.f, 0.f, 0.f, 0.f};
    f32x4 wr[4];
    {
      const float* wbase = Wout + (long)(0 * 64 + arow) * 64;
      wr[0] = *(const f32x4*)(wbase + quad * 8);
      wr[1] = *(const f32x4*)(wbase + quad * 8 + 4);
      wr[2] = *(const f32x4*)(wbase + 32 + quad * 8);
      wr[3] = *(const f32x4*)(wbase + 36 + quad * 8);
    }
#pragma unroll
    for (int kp = 0; kp < 4; kp++) {
      const float inv = qvv[kp];
      bf16x8 awh0, awl0, awh1, awl1;
      split8(wr[0], wr[1], inv, awh0, awl0);
      split8(wr[2], wr[3], inv, awh1, awl1);
      if (kp < 3) {
        const float* wbase = Wout + (long)((kp + 1) * 64 + arow) * 64;
        wr[0] = *(const f32x4*)(wbase + quad * 8);
        wr[1] = *(const f32x4*)(wbase + quad * 8 + 4);
        wr[2] = *(const f32x4*)(wbase + 32 + quad * 8);
        wr[3] = *(const f32x4*)(wbase + 36 + quad * 8);
      }
#pragma unroll
      for (int nt = 0; nt < 4; nt++) {
        const bf16x8 bh0 = *(const bf16x8*)&ThB[kp * SLOT + (nt * 16 + col) * 72 + quad * 8];
        const bf16x8 bl0 = *(const bf16x8*)&TlB[kp * SLOT + (nt * 16 + col) * 72 + quad * 8];
        dcF[nt] = __builtin_amdgcn_mfma_f32_16x16x32_bf16(awh0, bh0, dcF[nt], 0, 0, 0);
        dcF[nt] = __builtin_amdgcn_mfma_f32_16x16x32_bf16(awh0, bl0, dcF[nt], 0, 0, 0);
        dcF[nt] = __builtin_amdgcn_mfma_f32_16x16x32_bf16(awl0, bh0, dcF[nt], 0, 0, 0);
        const bf16x8 bh1 = *(const bf16x8*)&ThB[kp * SLOT + (nt * 16 + col) * 72 + 32 + quad * 8];
        const bf16x8 bl1 = *(const bf16x8*)&TlB[kp * SLOT + (nt * 16 + col) * 72 + 32 + quad * 8];
        dcF[nt] = __builtin_amdgcn_mfma_f32_16x16x32_bf16(awh1, bh1, dcF[nt], 0, 0, 0);
        dcF[nt] = __builtin_amdgcn_mfma_f32_16x16x32_bf16(awh1, bl1, dcF[nt], 0, 0, 0);
        dcF[nt] = __builtin_amdgcn_mfma_f32_16x16x32_bf16(awl1, bh1, dcF[nt], 0, 0, 0);
      }
    }
    // c partials into cA (c3 dead): wave it handles k'=it
    {
      const float* wrow = Wout + (long)(it * 64 + lane) * 64;
      float pc = 0.f;
#pragma unroll
      for (int u4 = 0; u4 < 16; u4++) {
        const f32x4 wv = *(const f32x4*)(wrow + u4 * 4);
        pc += wv[0] * cB[it * 64 + u4 * 4]     + wv[1] * cB[it * 64 + u4 * 4 + 1] +
              wv[2] * cB[it * 64 + u4 * 4 + 2] + wv[3] * cB[it * 64 + u4 * 4 + 3];
      }
      cA[it * 64 + lane] = qvv[it] * pc + bout[it * 64 + lane];
    }
    // write TF: f32 copy (group-A bytes 0..17407) + split (group-A slot 2)
    float* TfF = (float*)ThA;
    unsigned short* Th2 = ThA + 2 * SLOT;
    unsigned short* Tl2 = TlA + 2 * SLOT;
#pragma unroll
    for (int nt = 0; nt < 4; nt++)
#pragma unroll
      for (int r = 0; r < 4; r++) {
        const float val = dcF[nt][r];
        const int v_ = it * 16 + quad * 4 + r, w_ = nt * 16 + col;
        TfF[v_ * 68 + w_] = val;
        const unsigned short h = f2bf(val);
        Th2[w_ * 72 + v_] = h;
        Tl2[w_ * 72 + v_] = f2bf(val - bf2f(h));
      }
    __syncthreads();
    if (tid < 64) cF[tid] = cA[tid] + cA[64 + tid] + cA[128 + tid] + cA[192 + tid];
    __syncthreads();

    float qp = qpart(Th2, Tl2, it, col, quad, Greg);
    if (tid < 64) {
      float sd = 0.f;
#pragma unroll
      for (int u4 = 0; u4 < 16; u4++) {
        const f32x4 tv = *(const f32x4*)&TfF[tid * 68 + u4 * 4];
        const f32x4 sv = *(const f32x4*)&slv[u4 * 4];
        sd += sv[0] * tv[0] + sv[1] * tv[1] + sv[2] * tv[2] + sv[3] * tv[3];
      }
      qp += cF[tid] * (2.f * sd + BF * cF[tid]);
    }
    blkred(qp, red4, qvv, 4, tid, lane, it);
    const float inv = qvv[4];

#pragma unroll
    for (int m = 0; m < 16; m++) {
      const int li = m * 256 + tid;
      MoS[li] = inv * TfF[(li >> 6) * 68 + (li & 63)];
    }
    if (tid < 64) coS[tid] = inv * cF[tid];
  }
}

// ---------- kApply: out[b][v] = x[b] @ MoS[:,v] + coS[v] (bf16-x input) -----
// R0 config: 1024 blocks x 16 t-iters.
__global__ __launch_bounds__(256) void kApply(const unsigned short* __restrict__ x16,
                                              const float* __restrict__ MoS,
                                              const float* __restrict__ coS,
                                              float* __restrict__ out) {
  const int tid = threadIdx.x, lane = tid & 63, vt = tid >> 6;
  const int col = lane & 15, q = lane >> 4;

  bf16x8 bfr[2];
  const float* mr = MoS + (vt * 16 + col) * 64 + q * 8;
  bfr[0] = cvt8(*(const f32x4*)mr, *(const f32x4*)(mr + 4), 1.f);
  bfr[1] = cvt8(*(const f32x4*)(mr + 32), *(const f32x4*)(mr + 36), 1.f);
  const float cf = coS[vt * 16 + col];

  for (int t = 0; t < 16; t++) {
    const int b0 = (blockIdx.x * 16 + t) * 16;
    const unsigned short* xr = x16 + (long)(b0 + col) * 64 + q * 8;
    const bf16x8 a0 = *(const bf16x8*)xr;
    const bf16x8 a1 = *(const bf16x8*)(xr + 32);
    f32x4 acc = (f32x4){0.f, 0.f, 0.f, 0.f};
    acc = __builtin_amdgcn_mfma_f32_16x16x32_bf16(a0, bfr[0], acc, 0, 0, 0);
    acc = __builtin_amdgcn_mfma_f32_16x16x32_bf16(a1, bfr[1], acc, 0, 0, 0);
#pragma unroll
    for (int r = 0; r < 4; r++)
      out[(long)(b0 + q * 4 + r) * 64 + vt * 16 + col] = acc[r] + cf;
  }
}

extern "C" void kernel_launch(void* const* d_in, const int* in_sizes, int n_in,
                              void* d_out, int out_size, void* d_ws, size_t ws_size,
                              hipStream_t stream) {
  const float* x    = (const float*)d_in[0];
  const float* Win  = (const float*)d_in[1];
  const float* bin  = (const float*)d_in[2];
  const float* Wmid = (const float*)d_in[3];
  const float* bmid = (const float*)d_in[4];
  const float* Wout = (const float*)d_in[5];
  const float* bout = (const float*)d_in[6];
  float* out = (float*)d_out;
  float* ws  = (float*)d_ws;
  float* Gpart = out;   // 8.5 MB scratch inside d_out; fully overwritten by kApply
  unsigned short* x16 = (unsigned short*)(ws + OFF_X16);

  // kChain1 LDS: 16 slots * 4608 u16 * 2B + 652 floats = 150064 B
  const size_t SMEM2 = (size_t)(16 * SLOT) * 2 + 652 * 4;
  hipFuncSetAttribute((const void*)kChain1,
                      hipFuncAttributeMaxDynamicSharedMemorySize, (int)SMEM2);

  kG   <<<512, 256, 0, stream>>>(x, Gpart, x16);
  kGred<<<65, 256, 0, stream>>>(Gpart, ws + OFF_G, ws + OFF_S);
  kChain1<<<1, 256, SMEM2, stream>>>(Win, bin, Wmid, bmid, Wout, bout,
                                     ws + OFF_G, ws + OFF_S,
                                     ws + OFF_MO, ws + OFF_CO);
  kApply<<<1024, 256, 0, stream>>>(x16, ws + OFF_MO, ws + OFF_CO, out);
}

// Round 5
// 251.980 us; speedup vs baseline: 1.1596x; 1.1596x over previous
//
#include <hip/hip_runtime.h>

// GraphNN collapsed to exact affine form, restructured via PATH EXPANSION:
//   T_l[n] = sum_paths (prod inv) * P_path   (P = pure W-products, G-independent)
//   q_l(n)^2 = sum_{j,j'} C_j C_j' Q_l[n][j,j'] + 2 c.ts + BF|c|^2,
//   Q_l[n][j,j'] = sum_v P_j[v,:] G P_j'[v,:]^T  (G-dependent, inv-independent).
// Round 16 (R4 resubmit after infra failure + LDS-union fix in kGP):
//   kGP   : kG (512 blocks, unchanged) + 256 path-chain blocks (f32 matmuls);
//           kG arrays union'd with path mbuf -> 52.2KB static LDS total.
//   kGred : reduce Gpart -> G,s; zero Q/N2 region
//   kTab  : Q1..Q4 tables + sv vectors (chip-parallel)
//   kLM   : 16 blocks: redundant scalar ladder -> mcoef; Mo rows; n2 partials
//   kApply: unchanged except 1/n_out folded into the bf16 fragment scale
// 5 dispatches, no grid.sync, serial work ~scalar-sized. ws use 43.4MB < 256MiB.

#define BF 262144.0f

// ws float offsets
#define OFF_G     0         // 4096
#define OFF_S     4096      // 64
#define OFF_Q1    4160      // 4   (64 slot)
#define OFF_Q2    4224      // 64
#define OFF_Q3    4288      // 1024
#define OFF_Q4    5312      // 16384
#define OFF_N2    21696     // 1 (+pad to 64)
#define OFF_COUT  21760     // 64
#define OFF_SV1   21824     // 256
#define OFF_SV2   22080     // 1024
#define OFF_SV3   23104     // 4096
#define OFF_SV4   27200     // 16384
#define OFF_MO    43584     // 4096 (unnormalized Mo, f32)
#define OFF_P2    49152     // 16*4096
#define OFF_P3    114688    // 64*4096
#define OFF_P4    376832    // 256*4096
#define OFF_PO    1425408   // 256*4096
#define OFF_X16   2473984   // bf16 x copy: 16.78M u16
#define NZERO     17600     // floats zeroed from OFF_Q1 (Q1..Q4+N2)

typedef __attribute__((ext_vector_type(8))) short bf16x8;
typedef __attribute__((ext_vector_type(4))) float f32x4;
typedef __attribute__((ext_vector_type(4))) unsigned short u16x4;

__device__ __forceinline__ unsigned short f2bf(float f) {
  unsigned u = __builtin_bit_cast(unsigned, f);
  u += 0x7FFF + ((u >> 16) & 1);
  return (unsigned short)(u >> 16);
}

__device__ __forceinline__ bf16x8 cvt8(f32x4 a, f32x4 b, float s) {
  bf16x8 t;
#pragma unroll
  for (int j = 0; j < 4; j++) {
    t[j]     = (short)f2bf(a[j] * s);
    t[j + 4] = (short)f2bf(b[j] * s);
  }
  return t;
}

// ---- LDS 64x64 helpers, stride 68 ----
__device__ __forceinline__ void ld64(float* dst, const float* __restrict__ src, int tid) {
#pragma unroll
  for (int m = 0; m < 4; m++) {
    const int li = m * 1024 + tid * 4;
    *(f32x4*)&dst[(li >> 6) * 68 + (li & 63)] = *(const f32x4*)(src + li);
  }
}
__device__ __forceinline__ void st64(float* __restrict__ dst, const float* src, int tid) {
#pragma unroll
  for (int m = 0; m < 4; m++) {
    const int li = m * 1024 + tid * 4;
    *(f32x4*)(dst + li) = *(const f32x4*)&src[(li >> 6) * 68 + (li & 63)];
  }
}
// C = A @ B (64x64x64, f32, all LDS stride 68)
__device__ __forceinline__ void mm64(float* C, const float* A, const float* B, int tid) {
  const int v0 = (tid >> 4) * 4, w0 = (tid & 15) * 4;
  f32x4 a0 = {0.f,0.f,0.f,0.f}, a1 = a0, a2 = a0, a3 = a0;
#pragma unroll 8
  for (int u = 0; u < 64; u++) {
    const f32x4 b = *(const f32x4*)&B[u * 68 + w0];
    a0 += b * A[(v0 + 0) * 68 + u];
    a1 += b * A[(v0 + 1) * 68 + u];
    a2 += b * A[(v0 + 2) * 68 + u];
    a3 += b * A[(v0 + 3) * 68 + u];
  }
  *(f32x4*)&C[(v0 + 0) * 68 + w0] = a0;
  *(f32x4*)&C[(v0 + 1) * 68 + w0] = a1;
  *(f32x4*)&C[(v0 + 2) * 68 + w0] = a2;
  *(f32x4*)&C[(v0 + 3) * 68 + w0] = a3;
}

// ---------- kGP: blocks <512 = old kG; blocks 512..767 = path chains --------
// LDS union: kG uses [xts 4KB | sred 4KB]; path uses [mbuf 3*17408B]. 52224B.
__global__ __launch_bounds__(256) void kGP(const float* __restrict__ x,
                                           float* __restrict__ Gpart,
                                           unsigned short* __restrict__ x16,
                                           const float* __restrict__ Win,
                                           const float* __restrict__ Wmid,
                                           const float* __restrict__ Wout,
                                           float* __restrict__ ws) {
  __shared__ __align__(16) char shm[3 * 4352 * 4];
  const int tid = threadIdx.x;

  if (blockIdx.x < 512) {
    // ---- kG body (identical to the 227us baseline) ----
    typedef unsigned short xts_t[4][16][8];
    xts_t* xts = (xts_t*)shm;                      // [4][4][16][8] u16 = 4096B
    float (*sred)[4] = (float(*)[4])(shm + 4096);  // [256][4] f32 = 4096B
    const int lane = tid & 63, mt = tid >> 6;
    const int col = lane & 15, q = lane >> 4;
    const int row0 = tid >> 4;
    const int cf0  = (tid & 15) * 4;

    f32x4 acc[4];
#pragma unroll
    for (int nt = 0; nt < 4; nt++) acc[nt] = (f32x4){0.f, 0.f, 0.f, 0.f};
    float s0 = 0.f, s1 = 0.f, s2 = 0.f, s3 = 0.f;

    const long brow = (long)blockIdx.x * 512;
    const float* bx = x + brow * 64;
    f32x4 r0 = *(const f32x4*)(bx + tid * 4);
    f32x4 r1 = *(const f32x4*)(bx + 1024 + tid * 4);

    for (int c = 0; c < 16; c++) {
      __syncthreads();
      s0 += r0[0] + r1[0]; s1 += r0[1] + r1[1];
      s2 += r0[2] + r1[2]; s3 += r0[3] + r1[3];
      u16x4 h0, h1;
#pragma unroll
      for (int j = 0; j < 4; j++) {
        const int cf = cf0 + j;
        const unsigned short b0 = f2bf(r0[j]);
        const unsigned short b1 = f2bf(r1[j]);
        h0[j] = b0; h1[j] = b1;
        xts[cf >> 4][row0 >> 3][cf & 15][row0 & 7]        = b0;
        xts[cf >> 4][2 + (row0 >> 3)][cf & 15][row0 & 7]  = b1;
      }
      *(u16x4*)(x16 + (brow + c * 32 + row0) * 64 + cf0)      = h0;
      *(u16x4*)(x16 + (brow + c * 32 + 16 + row0) * 64 + cf0) = h1;
      f32x4 r0n = r0, r1n = r1;
      if (c < 15) {
        r0n = *(const f32x4*)(bx + (c + 1) * 2048 + tid * 4);
        r1n = *(const f32x4*)(bx + (c + 1) * 2048 + 1024 + tid * 4);
      }
      __syncthreads();
      const bf16x8 af = *(const bf16x8*)xts[mt][q][col];
#pragma unroll
      for (int nt = 0; nt < 4; nt++) {
        const bf16x8 bfr = *(const bf16x8*)xts[nt][q][col];
        acc[nt] = __builtin_amdgcn_mfma_f32_16x16x32_bf16(af, bfr, acc[nt], 0, 0, 0);
      }
      r0 = r0n; r1 = r1n;
    }

    float* myp = Gpart + (long)blockIdx.x * 4160;
#pragma unroll
    for (int nt = 0; nt < 4; nt++)
#pragma unroll
      for (int r = 0; r < 4; r++)
        myp[(mt * 16 + q * 4 + r) * 64 + nt * 16 + col] = acc[nt][r];

    sred[tid][0] = s0; sred[tid][1] = s1; sred[tid][2] = s2; sred[tid][3] = s3;
    __syncthreads();
    if (tid < 64) {
      float t = 0.f;
#pragma unroll
      for (int k2 = 0; k2 < 16; k2++) t += sred[(tid >> 2) + 16 * k2][tid & 3];
      myp[4096 + tid] = t;
    }
  } else {
    // ---- path-chain block: pid = (p1,p2,p3,p4) ----
    float* mb0 = (float*)shm;
    float* mb1 = mb0 + 4352;
    float* mb2 = mb1 + 4352;
    const int pid = blockIdx.x - 512;
    const int p1 = (pid >> 6) & 3, p2 = (pid >> 4) & 3, p3 = (pid >> 2) & 3, p4 = pid & 3;
    ld64(mb0, Win + p1 * 4096, tid);                         // B = T1 = Win[p1]
    ld64(mb1, Wmid + (p1 * 4 + p2) * 4096, tid);             // A = Wm0[p1,p2]
    __syncthreads();
    mm64(mb2, mb1, mb0, tid);                                // M2
    __syncthreads();
    if (p3 == 0 && p4 == 0) st64(ws + OFF_P2 + (p1 * 4 + p2) * 4096, mb2, tid);
    ld64(mb1, Wmid + 65536 + (p2 * 4 + p3) * 4096, tid);     // A = Wm1[p2,p3]
    __syncthreads();
    mm64(mb0, mb1, mb2, tid);                                // M3
    __syncthreads();
    if (p4 == 0) st64(ws + OFF_P3 + (p1 * 16 + p2 * 4 + p3) * 4096, mb0, tid);
    ld64(mb1, Wmid + 131072 + (p3 * 4 + p4) * 4096, tid);    // A = Wm2[p3,p4]
    __syncthreads();
    mm64(mb2, mb1, mb0, tid);                                // M4
    __syncthreads();
    st64(ws + OFF_P4 + pid * 4096, mb2, tid);
    ld64(mb1, Wout + p4 * 4096, tid);                        // A = Wout[p4]
    __syncthreads();
    mm64(mb0, mb1, mb2, tid);                                // PO
    __syncthreads();
    st64(ws + OFF_PO + pid * 4096, mb0, tid);
  }
}

// ---------- kGred: reduce 512 partials -> G, s; zero Q/N2 region ------------
__global__ __launch_bounds__(256) void kGred(const float* __restrict__ Gpart,
                                             float* __restrict__ ws) {
  __shared__ float red[4][64];
  const int tid = threadIdx.x;
  for (int i = blockIdx.x * 256 + tid; i < NZERO; i += 65 * 256)
    ws[OFF_Q1 + i] = 0.f;
  const int e = blockIdx.x * 64 + (tid & 63);
  const int quarter = tid >> 6;
  float acc = 0.f;
#pragma unroll 4
  for (int j = 0; j < 128; j++)
    acc += Gpart[(long)(quarter * 128 + j) * 4160 + e];
  red[quarter][tid & 63] = acc;
  __syncthreads();
  if (tid < 64) {
    const float t = red[0][tid] + red[1][tid] + red[2][tid] + red[3][tid];
    const int ee = blockIdx.x * 64 + tid;
    if (ee < 4096) ws[OFF_G + ee] = t;
    else           ws[OFF_S + ee - 4096] = t;
  }
}

// ---------- kTab: Q tables + sv vectors -------------------------------------
// blocks: 0..3 L1 | 4..19 L2 | 20..35 L3 | 36..163 L4 | 164..167 sv
__global__ __launch_bounds__(256) void kTab(const float* __restrict__ Win,
                                            float* __restrict__ ws) {
  __shared__ __align__(16) float Gl[64 * 68];
  __shared__ __align__(16) float Al[64 * 68];
  __shared__ __align__(16) float Bl[64 * 68];
  __shared__ float red[256];
  __shared__ float sl[64];
  const int tid = threadIdx.x, b = blockIdx.x;
  const int it = tid >> 6, lane = tid & 63;

  ld64(Gl, ws + OFF_G, tid);
  if (tid < 64) sl[tid] = ws[OFF_S + tid];
  __syncthreads();

  if (b < 4) {
    // L1: Q1[p1] = sum_v Win[p1][v,:] G Win[p1][v,:]^T
    ld64(Al, Win + b * 4096, tid);
    __syncthreads();
    const int vq = it, w = lane;
    float part = 0.f;
    for (int m = 0; m < 16; m++) {
      const int v = vq + m * 4;
      float bw = 0.f;
#pragma unroll 8
      for (int wp = 0; wp < 64; wp++) bw += Al[v * 68 + wp] * Gl[wp * 68 + w];
      part += bw * Al[v * 68 + w];
    }
    red[tid] = part;
    __syncthreads();
    for (int st = 128; st > 0; st >>= 1) {
      if (tid < st) red[tid] += red[tid + st];
      __syncthreads();
    }
    if (tid == 0) ws[OFF_Q1 + b] = red[0];
  } else if (b < 164) {
    int NP, nv, v0, node, qoff;
    const float* Pbase;
    if (b < 20)      { NP = 4;  node = (b - 4)  >> 2; v0 = ((b - 4)  & 3) * 16; nv = 16; Pbase = ws + OFF_P2; qoff = OFF_Q2 + node * 16; }
    else if (b < 36) { NP = 16; node = (b - 20) >> 2; v0 = ((b - 20) & 3) * 16; nv = 16; Pbase = ws + OFF_P3; qoff = OFF_Q3 + node * 256; }
    else             { NP = 64; node = (b - 36) >> 5; v0 = ((b - 36) & 31) * 2; nv = 2;  Pbase = ws + OFF_P4; qoff = OFF_Q4 + node * 4096; }

    float q1acc = 0.f;                    // NP=4 (tid<16) / NP=16 (all) scalar
    f32x4 qq0 = {0.f,0.f,0.f,0.f}, qq1 = qq0, qq2 = qq0, qq3 = qq0;  // NP=64 tile

    for (int vi = 0; vi < nv; vi++) {
      const int v = v0 + vi;
      __syncthreads();
      // A_v load: NP rows, row j = P[(j*4+node)][v,:]
      for (int e = tid * 4; e < NP * 64; e += 1024) {
        const int j = e >> 6, c = e & 63;
        *(f32x4*)&Al[j * 68 + c] = *(const f32x4*)(Pbase + (long)(j * 4 + node) * 4096 + v * 64 + c);
      }
      __syncthreads();
      // B = A_v @ G
      if (NP == 64) {
        const int j = tid >> 2, w0 = (tid & 3) * 16;
        f32x4 a0 = {0.f,0.f,0.f,0.f}, a1 = a0, a2 = a0, a3 = a0;
#pragma unroll 8
        for (int wp = 0; wp < 64; wp++) {
          const float a = Al[j * 68 + wp];
          a0 += a * *(const f32x4*)&Gl[wp * 68 + w0];
          a1 += a * *(const f32x4*)&Gl[wp * 68 + w0 + 4];
          a2 += a * *(const f32x4*)&Gl[wp * 68 + w0 + 8];
          a3 += a * *(const f32x4*)&Gl[wp * 68 + w0 + 12];
        }
        *(f32x4*)&Bl[j * 68 + w0]      = a0;
        *(f32x4*)&Bl[j * 68 + w0 + 4]  = a1;
        *(f32x4*)&Bl[j * 68 + w0 + 8]  = a2;
        *(f32x4*)&Bl[j * 68 + w0 + 12] = a3;
      } else if (NP == 16) {
        const int j = tid >> 4, w0 = (tid & 15) * 4;
        f32x4 a0 = {0.f,0.f,0.f,0.f};
#pragma unroll 8
        for (int wp = 0; wp < 64; wp++)
          a0 += Al[j * 68 + wp] * *(const f32x4*)&Gl[wp * 68 + w0];
        *(f32x4*)&Bl[j * 68 + w0] = a0;
      } else {
        const int j = tid >> 6, w = tid & 63;
        float a0 = 0.f;
#pragma unroll 8
        for (int wp = 0; wp < 64; wp++) a0 += Al[j * 68 + wp] * Gl[wp * 68 + w];
        Bl[j * 68 + w] = a0;
      }
      __syncthreads();
      // Q += B A^T
      if (NP == 64) {
        const int j0 = (tid >> 4) * 4, jp = tid & 15;
#pragma unroll 4
        for (int w4 = 0; w4 < 16; w4++) {
          const f32x4 b0 = *(const f32x4*)&Bl[(j0 + 0) * 68 + w4 * 4];
          const f32x4 b1 = *(const f32x4*)&Bl[(j0 + 1) * 68 + w4 * 4];
          const f32x4 b2 = *(const f32x4*)&Bl[(j0 + 2) * 68 + w4 * 4];
          const f32x4 b3 = *(const f32x4*)&Bl[(j0 + 3) * 68 + w4 * 4];
#pragma unroll
          for (int bb = 0; bb < 4; bb++) {
            const f32x4 av = *(const f32x4*)&Al[(jp + 16 * bb) * 68 + w4 * 4];
            qq0[bb] += b0[0]*av[0] + b0[1]*av[1] + b0[2]*av[2] + b0[3]*av[3];
            qq1[bb] += b1[0]*av[0] + b1[1]*av[1] + b1[2]*av[2] + b1[3]*av[3];
            qq2[bb] += b2[0]*av[0] + b2[1]*av[1] + b2[2]*av[2] + b2[3]*av[3];
            qq3[bb] += b3[0]*av[0] + b3[1]*av[1] + b3[2]*av[2] + b3[3]*av[3];
          }
        }
      } else if (NP == 16) {
        const int j = tid >> 4, jp = tid & 15;
#pragma unroll 4
        for (int w4 = 0; w4 < 16; w4++) {
          const f32x4 bv = *(const f32x4*)&Bl[j * 68 + w4 * 4];
          const f32x4 av = *(const f32x4*)&Al[jp * 68 + w4 * 4];
          q1acc += bv[0]*av[0] + bv[1]*av[1] + bv[2]*av[2] + bv[3]*av[3];
        }
      } else {
        if (tid < 16) {
          const int j = tid >> 2, jp = tid & 3;
#pragma unroll 8
          for (int w = 0; w < 64; w++) q1acc += Bl[j * 68 + w] * Al[jp * 68 + w];
        }
      }
    }
    if (NP == 64) {
      const int j0 = (tid >> 4) * 4, jp = tid & 15;
#pragma unroll
      for (int bb = 0; bb < 4; bb++) {
        atomicAdd(&ws[qoff + (j0 + 0) * 64 + jp + 16 * bb], qq0[bb]);
        atomicAdd(&ws[qoff + (j0 + 1) * 64 + jp + 16 * bb], qq1[bb]);
        atomicAdd(&ws[qoff + (j0 + 2) * 64 + jp + 16 * bb], qq2[bb]);
        atomicAdd(&ws[qoff + (j0 + 3) * 64 + jp + 16 * bb], qq3[bb]);
      }
    } else if (NP == 16) {
      atomicAdd(&ws[qoff + (tid >> 4) * 16 + (tid & 15)], q1acc);
    } else if (tid < 16) {
      atomicAdd(&ws[qoff + tid], q1acc);
    }
  } else {
    // sv vectors: 340 matvecs P_j @ s
    const int vb = b - 164;
    const int lo = vb * 85, hi = (vb == 3) ? 340 : lo + 85;
    for (int vec = lo + it; vec < hi; vec += 4) {
      const float* mat; int dst;
      if (vec < 4)       { mat = Win + vec * 4096;                dst = OFF_SV1 + vec * 64; }
      else if (vec < 20) { mat = ws + OFF_P2 + (vec - 4) * 4096;  dst = OFF_SV2 + (vec - 4) * 64; }
      else if (vec < 84) { mat = ws + OFF_P3 + (vec - 20) * 4096; dst = OFF_SV3 + (vec - 20) * 64; }
      else               { mat = ws + OFF_P4 + (vec - 84) * 4096; dst = OFF_SV4 + (vec - 84) * 64; }
      float acc = 0.f;
#pragma unroll
      for (int u4 = 0; u4 < 16; u4++) {
        const f32x4 mv = *(const f32x4*)(mat + lane * 64 + u4 * 4);
        acc += mv[0]*sl[u4*4] + mv[1]*sl[u4*4+1] + mv[2]*sl[u4*4+2] + mv[3]*sl[u4*4+3];
      }
      ws[dst + lane] = acc;
    }
  }
}

// ---------- kLM: redundant scalar ladder + Mo rows + n2 partials ------------
__global__ __launch_bounds__(256) void kLM(
    const float* __restrict__ bin, const float* __restrict__ Wmid,
    const float* __restrict__ bmid, const float* __restrict__ Wout,
    const float* __restrict__ bout, float* __restrict__ ws) {
  __shared__ float binl[256], c2l[256], c3l[256], c4l[256], col[64];
  __shared__ float sv1l[256], sv2l[1024];
  __shared__ float inv1[4], inv2[4], inv3[4], inv4[4];
  __shared__ float C2l[4], C3l[16], C4l[64], mco[256];
  __shared__ __align__(16) float Grow[64 * 68];
  __shared__ float sl[64];
  __shared__ float tfl[4][64];
  __shared__ float redb[256];
  const int tid = threadIdx.x, it = tid >> 6, lane = tid & 63;

  binl[tid] = bin[tid];
  sv1l[tid] = ws[OFF_SV1 + tid];
#pragma unroll
  for (int m = 0; m < 4; m++) sv2l[m * 256 + tid] = ws[OFF_SV2 + m * 256 + tid];
  if (tid < 64) sl[tid] = ws[OFF_S + tid];
  ld64(Grow, ws + OFF_G, tid);
  __syncthreads();

  // rung 1: wave p = it
  {
    const float c = binl[it * 64 + lane];
    float part = c * (2.f * sv1l[it * 64 + lane] + BF * c);
#pragma unroll
    for (int off = 32; off; off >>= 1) part += __shfl_down(part, off, 64);
    if (lane == 0) inv1[it] = rsqrtf(ws[OFF_Q1 + it] + part);
  }
  __syncthreads();
  if (tid < 4) C2l[tid] = inv1[tid];
  __syncthreads();
  // c2[tgt=it]
  {
    float acc = 0.f;
#pragma unroll
    for (int src = 0; src < 4; src++) {
      const float* wr = Wmid + (long)((src * 4 + it) * 64 + lane) * 64;
      float pc = 0.f;
#pragma unroll
      for (int u4 = 0; u4 < 16; u4++) {
        const f32x4 wv = *(const f32x4*)(wr + u4 * 4);
        pc += wv[0]*binl[src*64+u4*4]   + wv[1]*binl[src*64+u4*4+1]
            + wv[2]*binl[src*64+u4*4+2] + wv[3]*binl[src*64+u4*4+3];
      }
      acc += inv1[src] * pc + bmid[(src * 4 + it) * 64 + lane];
    }
    c2l[it * 64 + lane] = acc;
  }
  __syncthreads();
  // rung 2
  {
    float ts = 0.f;
#pragma unroll
    for (int p1 = 0; p1 < 4; p1++) ts += C2l[p1] * sv2l[(p1 * 4 + it) * 64 + lane];
    const float c = c2l[it * 64 + lane];
    float part = c * (2.f * ts + BF * c);
    if (lane < 16) part += C2l[lane >> 2] * C2l[lane & 3] * ws[OFF_Q2 + it * 16 + lane];
#pragma unroll
    for (int off = 32; off; off >>= 1) part += __shfl_down(part, off, 64);
    if (lane == 0) inv2[it] = rsqrtf(part);
  }
  __syncthreads();
  if (tid < 16) C3l[tid] = C2l[tid >> 2] * inv2[tid & 3];
  __syncthreads();
  // c3[tgt=it]
  {
    float acc = 0.f;
#pragma unroll
    for (int src = 0; src < 4; src++) {
      const float* wr = Wmid + 65536 + (long)((src * 4 + it) * 64 + lane) * 64;
      float pc = 0.f;
#pragma unroll
      for (int u4 = 0; u4 < 16; u4++) {
        const f32x4 wv = *(const f32x4*)(wr + u4 * 4);
        pc += wv[0]*c2l[src*64+u4*4]   + wv[1]*c2l[src*64+u4*4+1]
            + wv[2]*c2l[src*64+u4*4+2] + wv[3]*c2l[src*64+u4*4+3];
      }
      acc += inv2[src] * pc + bmid[1024 + (src * 4 + it) * 64 + lane];
    }
    c3l[it * 64 + lane] = acc;
  }
  __syncthreads();
  // rung 3
  {
    float ts = 0.f;
#pragma unroll
    for (int j = 0; j < 16; j++) ts += C3l[j] * ws[OFF_SV3 + (j * 4 + it) * 64 + lane];
    const float c = c3l[it * 64 + lane];
    float part = c * (2.f * ts + BF * c);
#pragma unroll
    for (int k = 0; k < 4; k++) {
      const int idx = lane * 4 + k;
      part += C3l[idx >> 4] * C3l[idx & 15] * ws[OFF_Q3 + it * 256 + idx];
    }
#pragma unroll
    for (int off = 32; off; off >>= 1) part += __shfl_down(part, off, 64);
    if (lane == 0) inv3[it] = rsqrtf(part);
  }
  __syncthreads();
  if (tid < 64) C4l[tid] = C3l[tid >> 2] * inv3[tid & 3];
  __syncthreads();
  // c4[tgt=it]
  {
    float acc = 0.f;
#pragma unroll
    for (int src = 0; src < 4; src++) {
      const float* wr = Wmid + 131072 + (long)((src * 4 + it) * 64 + lane) * 64;
      float pc = 0.f;
#pragma unroll
      for (int u4 = 0; u4 < 16; u4++) {
        const f32x4 wv = *(const f32x4*)(wr + u4 * 4);
        pc += wv[0]*c3l[src*64+u4*4]   + wv[1]*c3l[src*64+u4*4+1]
            + wv[2]*c3l[src*64+u4*4+2] + wv[3]*c3l[src*64+u4*4+3];
      }
      acc += inv3[src] * pc + bmid[2048 + (src * 4 + it) * 64 + lane];
    }
    c4l[it * 64 + lane] = acc;
  }
  __syncthreads();
  // rung 4
  {
    float ts = 0.f;
    for (int j = 0; j < 64; j++) ts += C4l[j] * ws[OFF_SV4 + (j * 4 + it) * 64 + lane];
    const float c = c4l[it * 64 + lane];
    float part = c * (2.f * ts + BF * c);
    float rsum = 0.f;
    const float* qrow = ws + OFF_Q4 + it * 4096 + lane * 64;
#pragma unroll 8
    for (int jp = 0; jp < 64; jp++) rsum += C4l[jp] * qrow[jp];
    part += C4l[lane] * rsum;
#pragma unroll
    for (int off = 32; off; off >>= 1) part += __shfl_down(part, off, 64);
    if (lane == 0) inv4[it] = rsqrtf(part);
  }
  __syncthreads();
  mco[tid] = C4l[tid >> 2] * inv4[tid & 3];
  // c_out partial (reuse c2l as scratch): wave p4 = it
  {
    const float* wr = Wout + (long)(it * 64 + lane) * 64;
    float pc = 0.f;
#pragma unroll
    for (int u4 = 0; u4 < 16; u4++) {
      const f32x4 wv = *(const f32x4*)(wr + u4 * 4);
      pc += wv[0]*c4l[it*64+u4*4]   + wv[1]*c4l[it*64+u4*4+1]
          + wv[2]*c4l[it*64+u4*4+2] + wv[3]*c4l[it*64+u4*4+3];
    }
    c2l[it * 64 + lane] = inv4[it] * pc + bout[it * 64 + lane];
  }
  __syncthreads();
  if (tid < 64) col[tid] = c2l[tid] + c2l[64 + tid] + c2l[128 + tid] + c2l[192 + tid];
  __syncthreads();
  if (blockIdx.x == 0 && tid < 64) ws[OFF_COUT + tid] = col[tid];

  // ---- M phase: form Mo rows v = blockIdx.x*4 + it ----
  const int v = blockIdx.x * 4 + it;
  {
    float acc = 0.f;
    const float* po = ws + OFF_PO + v * 64 + lane;
#pragma unroll 4
    for (int i = 0; i < 256; i++) acc += mco[i] * po[(long)i * 4096];
    tfl[it][lane] = acc;
    ws[OFF_MO + v * 64 + lane] = acc;
  }
  __syncthreads();
  // n2 partial: sum_v row G row^T + 2 c_out[v] (row . s)
  {
    float bw = 0.f;
#pragma unroll 8
    for (int wp = 0; wp < 64; wp++) bw += tfl[it][wp] * Grow[wp * 68 + lane];
    float part = bw * tfl[it][lane] + 2.f * col[v] * tfl[it][lane] * sl[lane];
    redb[tid] = part;
    __syncthreads();
    for (int st = 128; st > 0; st >>= 1) {
      if (tid < st) redb[tid] += redb[tid + st];
      __syncthreads();
    }
    if (tid == 0) atomicAdd(&ws[OFF_N2], redb[0]);
    if (blockIdx.x == 0 && it == 0) {
      float p2_ = BF * col[lane] * col[lane];
#pragma unroll
      for (int off = 32; off; off >>= 1) p2_ += __shfl_down(p2_, off, 64);
      if (lane == 0) atomicAdd(&ws[OFF_N2], p2_);
    }
  }
}

// ---------- kApply: out = (x @ Mo^T + c_out) * rsqrt(n2) --------------------
__global__ __launch_bounds__(256) void kApply(const unsigned short* __restrict__ x16,
                                              const float* __restrict__ MoU,
                                              const float* __restrict__ coU,
                                              const float* __restrict__ n2p,
                                              float* __restrict__ out) {
  const int tid = threadIdx.x, lane = tid & 63, vt = tid >> 6;
  const int col = lane & 15, q = lane >> 4;
  const float inv = rsqrtf(n2p[0]);

  bf16x8 bfr[2];
  const float* mr = MoU + (vt * 16 + col) * 64 + q * 8;
  bfr[0] = cvt8(*(const f32x4*)mr, *(const f32x4*)(mr + 4), inv);
  bfr[1] = cvt8(*(const f32x4*)(mr + 32), *(const f32x4*)(mr + 36), inv);
  const float cf = inv * coU[vt * 16 + col];

  for (int t = 0; t < 16; t++) {
    const int b0 = (blockIdx.x * 16 + t) * 16;
    const unsigned short* xr = x16 + (long)(b0 + col) * 64 + q * 8;
    const bf16x8 a0 = *(const bf16x8*)xr;
    const bf16x8 a1 = *(const bf16x8*)(xr + 32);
    f32x4 acc = (f32x4){0.f, 0.f, 0.f, 0.f};
    acc = __builtin_amdgcn_mfma_f32_16x16x32_bf16(a0, bfr[0], acc, 0, 0, 0);
    acc = __builtin_amdgcn_mfma_f32_16x16x32_bf16(a1, bfr[1], acc, 0, 0, 0);
#pragma unroll
    for (int r = 0; r < 4; r++)
      out[(long)(b0 + q * 4 + r) * 64 + vt * 16 + col] = acc[r] + cf;
  }
}

extern "C" void kernel_launch(void* const* d_in, const int* in_sizes, int n_in,
                              void* d_out, int out_size, void* d_ws, size_t ws_size,
                              hipStream_t stream) {
  const float* x    = (const float*)d_in[0];
  const float* Win  = (const float*)d_in[1];
  const float* bin  = (const float*)d_in[2];
  const float* Wmid = (const float*)d_in[3];
  const float* bmid = (const float*)d_in[4];
  const float* Wout = (const float*)d_in[5];
  const float* bout = (const float*)d_in[6];
  float* out = (float*)d_out;
  float* ws  = (float*)d_ws;
  float* Gpart = out;   // 8.5 MB scratch inside d_out; fully overwritten by kApply
  unsigned short* x16 = (unsigned short*)(ws + OFF_X16);

  kGP  <<<768, 256, 0, stream>>>(x, Gpart, x16, Win, Wmid, Wout, ws);
  kGred<<<65, 256, 0, stream>>>(Gpart, ws);
  kTab <<<168, 256, 0, stream>>>(Win, ws);
  kLM  <<<16, 256, 0, stream>>>(bin, Wmid, bmid, Wout, bout, ws);
  kApply<<<1024, 256, 0, stream>>>(x16, ws + OFF_MO, ws + OFF_COUT, ws + OFF_N2, out);
}

// Round 6
// 242.574 us; speedup vs baseline: 1.2046x; 1.0388x over previous
//
#include <hip/hip_runtime.h>

// GraphNN via PATH EXPANSION (matrices AND bias-vectors):
//   T_l = sum_paths (prod inv) P_path;  c_l = sum_{bias entry points, paths}
//   (prod inv) V_path;  q_l^2 from Q tables (G-dependent, inv-independent).
// Round 17: R5's kLM was 78us of uncoalesced Wmid row reads down a serial
// 4-rung chain. Now ALL ladder matvecs are precomputed as bias-path vector
// tables (U*/V*/B*) inside kGP's path blocks (W tile already in LDS there).
// kLM rungs = coalesced table loads + scalar FMA. Q4 dot made coalesced.
// 5 dispatches: kGP, kGred, kTab, kLM, kApply.

#define BF 262144.0f

// ws float offsets
#define OFF_G     0         // 4096
#define OFF_S     4096      // 64
#define OFF_Q1    4160      // 64 (4 used)
#define OFF_Q2    4224      // 64
#define OFF_Q3    4288      // 1024
#define OFF_Q4    5312      // 16384
#define OFF_N2    21696     // 64 (1 used)
#define OFF_COUT  21760     // 64
#define OFF_SV1   21824     // 256
#define OFF_SV2   22080     // 1024
#define OFF_SV3   23104     // 4096
#define OFF_SV4   27200     // 16384
#define OFF_MO    43584     // 4096
#define OFF_B0    47680     // 256
#define OFF_B1    47936     // 256
#define OFF_B2    48192     // 256
#define OFF_U2    48512     // 1024
#define OFF_U3    49536     // 4096
#define OFF_U4    53632     // 16384
#define OFF_V3    70016     // 1024
#define OFF_V4A   71040     // 4096
#define OFF_V4B   75136     // 1024
#define OFF_UO    76160     // 16384
#define OFF_VOA   92544     // 4096
#define OFF_VOB   96640     // 1024
#define OFF_VOC   97664     // 256
#define OFF_P2    98304     // 16*4096
#define OFF_P3    163840    // 64*4096
#define OFF_P4    425984    // 256*4096
#define OFF_PO    1474560   // 256*4096
#define OFF_X16   2523136   // bf16 x copy: 16.78M u16
#define NZERO     17600     // floats zeroed from OFF_Q1 (Q1..Q4+N2)

typedef __attribute__((ext_vector_type(8))) short bf16x8;
typedef __attribute__((ext_vector_type(4))) float f32x4;
typedef __attribute__((ext_vector_type(4))) unsigned short u16x4;

__device__ __forceinline__ unsigned short f2bf(float f) {
  unsigned u = __builtin_bit_cast(unsigned, f);
  u += 0x7FFF + ((u >> 16) & 1);
  return (unsigned short)(u >> 16);
}

__device__ __forceinline__ bf16x8 cvt8(f32x4 a, f32x4 b, float s) {
  bf16x8 t;
#pragma unroll
  for (int j = 0; j < 4; j++) {
    t[j]     = (short)f2bf(a[j] * s);
    t[j + 4] = (short)f2bf(b[j] * s);
  }
  return t;
}

// ---- LDS 64x64 helpers, stride 68 ----
__device__ __forceinline__ void ld64(float* dst, const float* __restrict__ src, int tid) {
#pragma unroll
  for (int m = 0; m < 4; m++) {
    const int li = m * 1024 + tid * 4;
    *(f32x4*)&dst[(li >> 6) * 68 + (li & 63)] = *(const f32x4*)(src + li);
  }
}
__device__ __forceinline__ void st64(float* __restrict__ dst, const float* src, int tid) {
#pragma unroll
  for (int m = 0; m < 4; m++) {
    const int li = m * 1024 + tid * 4;
    *(f32x4*)(dst + li) = *(const f32x4*)&src[(li >> 6) * 68 + (li & 63)];
  }
}
// C = A @ B (64x64x64, f32, all LDS stride 68)
__device__ __forceinline__ void mm64(float* C, const float* A, const float* B, int tid) {
  const int v0 = (tid >> 4) * 4, w0 = (tid & 15) * 4;
  f32x4 a0 = {0.f,0.f,0.f,0.f}, a1 = a0, a2 = a0, a3 = a0;
#pragma unroll 8
  for (int u = 0; u < 64; u++) {
    const f32x4 b = *(const f32x4*)&B[u * 68 + w0];
    a0 += b * A[(v0 + 0) * 68 + u];
    a1 += b * A[(v0 + 1) * 68 + u];
    a2 += b * A[(v0 + 2) * 68 + u];
    a3 += b * A[(v0 + 3) * 68 + u];
  }
  *(f32x4*)&C[(v0 + 0) * 68 + w0] = a0;
  *(f32x4*)&C[(v0 + 1) * 68 + w0] = a1;
  *(f32x4*)&C[(v0 + 2) * 68 + w0] = a2;
  *(f32x4*)&C[(v0 + 3) * 68 + w0] = a3;
}
// dst[v] = W(LDS,68) @ vec(LDS): quarter-split dot + LDS reduce. 2 syncs.
__device__ __forceinline__ void mv64(float* dst, const float* W, const float* vec,
                                     float (*red)[64], int tid) {
  const int v = tid & 63, q = tid >> 6;
  float p = 0.f;
#pragma unroll
  for (int u = q * 16; u < q * 16 + 16; u++) p += W[v * 68 + u] * vec[u];
  red[q][v] = p;
  __syncthreads();
  if (tid < 64) dst[tid] = red[0][tid] + red[1][tid] + red[2][tid] + red[3][tid];
  __syncthreads();
}

// ---------- kGP: blocks <512 = kG; blocks 512..767 = path chains ------------
__global__ __launch_bounds__(256) void kGP(const float* __restrict__ x,
                                           float* __restrict__ Gpart,
                                           unsigned short* __restrict__ x16,
                                           const float* __restrict__ Win,
                                           const float* __restrict__ bin,
                                           const float* __restrict__ Wmid,
                                           const float* __restrict__ bmid,
                                           const float* __restrict__ Wout,
                                           float* __restrict__ ws) {
  __shared__ __align__(16) char shm[3 * 4352 * 4];
  __shared__ float vbuf[14][64];     // binl,B0l,B1l,B2l,u2,u3,v3,u4,v4a,v4b,uo,voa,vob,voc
  __shared__ float red4v[4][64];
  const int tid = threadIdx.x;

  if (blockIdx.x < 512) {
    // ---- kG body (identical to the 227us baseline) ----
    typedef unsigned short xts_t[4][16][8];
    xts_t* xts = (xts_t*)shm;
    float (*sred)[4] = (float(*)[4])(shm + 4096);
    const int lane = tid & 63, mt = tid >> 6;
    const int col = lane & 15, q = lane >> 4;
    const int row0 = tid >> 4;
    const int cf0  = (tid & 15) * 4;

    f32x4 acc[4];
#pragma unroll
    for (int nt = 0; nt < 4; nt++) acc[nt] = (f32x4){0.f, 0.f, 0.f, 0.f};
    float s0 = 0.f, s1 = 0.f, s2 = 0.f, s3 = 0.f;

    const long brow = (long)blockIdx.x * 512;
    const float* bx = x + brow * 64;
    f32x4 r0 = *(const f32x4*)(bx + tid * 4);
    f32x4 r1 = *(const f32x4*)(bx + 1024 + tid * 4);

    for (int c = 0; c < 16; c++) {
      __syncthreads();
      s0 += r0[0] + r1[0]; s1 += r0[1] + r1[1];
      s2 += r0[2] + r1[2]; s3 += r0[3] + r1[3];
      u16x4 h0, h1;
#pragma unroll
      for (int j = 0; j < 4; j++) {
        const int cf = cf0 + j;
        const unsigned short b0 = f2bf(r0[j]);
        const unsigned short b1 = f2bf(r1[j]);
        h0[j] = b0; h1[j] = b1;
        xts[cf >> 4][row0 >> 3][cf & 15][row0 & 7]        = b0;
        xts[cf >> 4][2 + (row0 >> 3)][cf & 15][row0 & 7]  = b1;
      }
      *(u16x4*)(x16 + (brow + c * 32 + row0) * 64 + cf0)      = h0;
      *(u16x4*)(x16 + (brow + c * 32 + 16 + row0) * 64 + cf0) = h1;
      f32x4 r0n = r0, r1n = r1;
      if (c < 15) {
        r0n = *(const f32x4*)(bx + (c + 1) * 2048 + tid * 4);
        r1n = *(const f32x4*)(bx + (c + 1) * 2048 + 1024 + tid * 4);
      }
      __syncthreads();
      const bf16x8 af = *(const bf16x8*)xts[mt][q][col];
#pragma unroll
      for (int nt = 0; nt < 4; nt++) {
        const bf16x8 bfr = *(const bf16x8*)xts[nt][q][col];
        acc[nt] = __builtin_amdgcn_mfma_f32_16x16x32_bf16(af, bfr, acc[nt], 0, 0, 0);
      }
      r0 = r0n; r1 = r1n;
    }

    float* myp = Gpart + (long)blockIdx.x * 4160;
#pragma unroll
    for (int nt = 0; nt < 4; nt++)
#pragma unroll
      for (int r = 0; r < 4; r++)
        myp[(mt * 16 + q * 4 + r) * 64 + nt * 16 + col] = acc[nt][r];

    sred[tid][0] = s0; sred[tid][1] = s1; sred[tid][2] = s2; sred[tid][3] = s3;
    __syncthreads();
    if (tid < 64) {
      float t = 0.f;
#pragma unroll
      for (int k2 = 0; k2 < 16; k2++) t += sred[(tid >> 2) + 16 * k2][tid & 3];
      myp[4096 + tid] = t;
    }
  } else {
    // ---- path-chain block: pid = (p1,p2,p3,p4) ----
    float* mb0 = (float*)shm;
    float* mb1 = mb0 + 4352;
    float* mb2 = mb1 + 4352;
    float* binl = vbuf[0]; float* B0l = vbuf[1]; float* B1l = vbuf[2]; float* B2l = vbuf[3];
    float* u2 = vbuf[4];  float* u3 = vbuf[5];  float* v3 = vbuf[6];
    float* u4 = vbuf[7];  float* v4a = vbuf[8]; float* v4b = vbuf[9];
    float* uo = vbuf[10]; float* voa = vbuf[11]; float* vob = vbuf[12]; float* voc = vbuf[13];
    const int pid = blockIdx.x - 512;
    const int p1 = (pid >> 6) & 3, p2 = (pid >> 4) & 3, p3 = (pid >> 2) & 3, p4 = pid & 3;
    const float* bm0 = bmid;
    const float* bm1 = bmid + 1024;
    const float* bm2 = bmid + 2048;

    if (tid < 64) {
      binl[tid] = bin[p1 * 64 + tid];
      B0l[tid] = bm0[(0*4+p2)*64+tid] + bm0[(1*4+p2)*64+tid] + bm0[(2*4+p2)*64+tid] + bm0[(3*4+p2)*64+tid];
      B1l[tid] = bm1[(0*4+p3)*64+tid] + bm1[(1*4+p3)*64+tid] + bm1[(2*4+p3)*64+tid] + bm1[(3*4+p3)*64+tid];
      B2l[tid] = bm2[(0*4+p4)*64+tid] + bm2[(1*4+p4)*64+tid] + bm2[(2*4+p4)*64+tid] + bm2[(3*4+p4)*64+tid];
    }
    ld64(mb0, Win + p1 * 4096, tid);
    ld64(mb1, Wmid + (p1 * 4 + p2) * 4096, tid);
    __syncthreads();
    mv64(u2, mb1, binl, red4v, tid);
    mm64(mb2, mb1, mb0, tid);                                // M2
    __syncthreads();
    if (p3 == 0 && p4 == 0) {
      st64(ws + OFF_P2 + (p1 * 4 + p2) * 4096, mb2, tid);
      if (tid < 64) ws[OFF_U2 + (p1 * 4 + p2) * 64 + tid] = u2[tid];
    }
    ld64(mb1, Wmid + 65536 + (p2 * 4 + p3) * 4096, tid);
    __syncthreads();
    mv64(u3, mb1, u2, red4v, tid);
    mv64(v3, mb1, B0l, red4v, tid);
    mm64(mb0, mb1, mb2, tid);                                // M3
    __syncthreads();
    if (p4 == 0) {
      st64(ws + OFF_P3 + (p1 * 16 + p2 * 4 + p3) * 4096, mb0, tid);
      if (tid < 64) ws[OFF_U3 + (p1 * 16 + p2 * 4 + p3) * 64 + tid] = u3[tid];
      if (p1 == 0 && tid < 64) ws[OFF_V3 + (p2 * 4 + p3) * 64 + tid] = v3[tid];
    }
    ld64(mb1, Wmid + 131072 + (p3 * 4 + p4) * 4096, tid);
    __syncthreads();
    mv64(u4, mb1, u3, red4v, tid);
    mv64(v4a, mb1, v3, red4v, tid);
    mv64(v4b, mb1, B1l, red4v, tid);
    mm64(mb2, mb1, mb0, tid);                                // M4
    __syncthreads();
    st64(ws + OFF_P4 + pid * 4096, mb2, tid);
    if (tid < 64) {
      ws[OFF_U4 + pid * 64 + tid] = u4[tid];
      if (p1 == 0) ws[OFF_V4A + ((p2 * 4 + p3) * 4 + p4) * 64 + tid] = v4a[tid];
      if (p1 == 0 && p2 == 0) ws[OFF_V4B + (p3 * 4 + p4) * 64 + tid] = v4b[tid];
    }
    ld64(mb1, Wout + p4 * 4096, tid);
    __syncthreads();
    mv64(uo, mb1, u4, red4v, tid);
    mv64(voa, mb1, v4a, red4v, tid);
    mv64(vob, mb1, v4b, red4v, tid);
    mv64(voc, mb1, B2l, red4v, tid);
    mm64(mb0, mb1, mb2, tid);                                // PO
    __syncthreads();
    st64(ws + OFF_PO + pid * 4096, mb0, tid);
    if (tid < 64) {
      ws[OFF_UO + pid * 64 + tid] = uo[tid];
      if (p1 == 0) ws[OFF_VOA + ((p2 * 4 + p3) * 4 + p4) * 64 + tid] = voa[tid];
      if (p1 == 0 && p2 == 0) ws[OFF_VOB + (p3 * 4 + p4) * 64 + tid] = vob[tid];
      if (p1 == 0 && p2 == 0 && p3 == 0) ws[OFF_VOC + p4 * 64 + tid] = voc[tid];
    }
    if (pid == 0) {
      const int t = tid >> 6, v = tid & 63;
      ws[OFF_B0 + tid] = bm0[(0*4+t)*64+v] + bm0[(1*4+t)*64+v] + bm0[(2*4+t)*64+v] + bm0[(3*4+t)*64+v];
      ws[OFF_B1 + tid] = bm1[(0*4+t)*64+v] + bm1[(1*4+t)*64+v] + bm1[(2*4+t)*64+v] + bm1[(3*4+t)*64+v];
      ws[OFF_B2 + tid] = bm2[(0*4+t)*64+v] + bm2[(1*4+t)*64+v] + bm2[(2*4+t)*64+v] + bm2[(3*4+t)*64+v];
    }
  }
}

// ---------- kGred: reduce 512 partials -> G, s; zero Q/N2 region ------------
__global__ __launch_bounds__(256) void kGred(const float* __restrict__ Gpart,
                                             float* __restrict__ ws) {
  __shared__ float red[4][64];
  const int tid = threadIdx.x;
  for (int i = blockIdx.x * 256 + tid; i < NZERO; i += 65 * 256)
    ws[OFF_Q1 + i] = 0.f;
  const int e = blockIdx.x * 64 + (tid & 63);
  const int quarter = tid >> 6;
  float acc = 0.f;
#pragma unroll 4
  for (int j = 0; j < 128; j++)
    acc += Gpart[(long)(quarter * 128 + j) * 4160 + e];
  red[quarter][tid & 63] = acc;
  __syncthreads();
  if (tid < 64) {
    const float t = red[0][tid] + red[1][tid] + red[2][tid] + red[3][tid];
    const int ee = blockIdx.x * 64 + tid;
    if (ee < 4096) ws[OFF_G + ee] = t;
    else           ws[OFF_S + ee - 4096] = t;
  }
}

// ---------- kTab: Q tables + sv vectors -------------------------------------
// blocks: 0..3 L1 | 4..19 L2 | 20..35 L3 | 36..163 L4 | 164..167 sv
__global__ __launch_bounds__(256) void kTab(const float* __restrict__ Win,
                                            float* __restrict__ ws) {
  __shared__ __align__(16) float Gl[64 * 68];
  __shared__ __align__(16) float Al[64 * 68];
  __shared__ __align__(16) float Bl[64 * 68];
  __shared__ float red[256];
  __shared__ float sl[64];
  const int tid = threadIdx.x, b = blockIdx.x;
  const int it = tid >> 6, lane = tid & 63;

  ld64(Gl, ws + OFF_G, tid);
  if (tid < 64) sl[tid] = ws[OFF_S + tid];
  __syncthreads();

  if (b < 4) {
    ld64(Al, Win + b * 4096, tid);
    __syncthreads();
    const int vq = it, w = lane;
    float part = 0.f;
    for (int m = 0; m < 16; m++) {
      const int v = vq + m * 4;
      float bw = 0.f;
#pragma unroll 8
      for (int wp = 0; wp < 64; wp++) bw += Al[v * 68 + wp] * Gl[wp * 68 + w];
      part += bw * Al[v * 68 + w];
    }
    red[tid] = part;
    __syncthreads();
    for (int st = 128; st > 0; st >>= 1) {
      if (tid < st) red[tid] += red[tid + st];
      __syncthreads();
    }
    if (tid == 0) ws[OFF_Q1 + b] = red[0];
  } else if (b < 164) {
    int NP, nv, v0, node, qoff;
    const float* Pbase;
    if (b < 20)      { NP = 4;  node = (b - 4)  >> 2; v0 = ((b - 4)  & 3) * 16; nv = 16; Pbase = ws + OFF_P2; qoff = OFF_Q2 + node * 16; }
    else if (b < 36) { NP = 16; node = (b - 20) >> 2; v0 = ((b - 20) & 3) * 16; nv = 16; Pbase = ws + OFF_P3; qoff = OFF_Q3 + node * 256; }
    else             { NP = 64; node = (b - 36) >> 5; v0 = ((b - 36) & 31) * 2; nv = 2;  Pbase = ws + OFF_P4; qoff = OFF_Q4 + node * 4096; }

    float q1acc = 0.f;
    f32x4 qq0 = {0.f,0.f,0.f,0.f}, qq1 = qq0, qq2 = qq0, qq3 = qq0;

    for (int vi = 0; vi < nv; vi++) {
      const int v = v0 + vi;
      __syncthreads();
      for (int e = tid * 4; e < NP * 64; e += 1024) {
        const int j = e >> 6, c = e & 63;
        *(f32x4*)&Al[j * 68 + c] = *(const f32x4*)(Pbase + (long)(j * 4 + node) * 4096 + v * 64 + c);
      }
      __syncthreads();
      if (NP == 64) {
        const int j = tid >> 2, w0 = (tid & 3) * 16;
        f32x4 a0 = {0.f,0.f,0.f,0.f}, a1 = a0, a2 = a0, a3 = a0;
#pragma unroll 8
        for (int wp = 0; wp < 64; wp++) {
          const float a = Al[j * 68 + wp];
          a0 += a * *(const f32x4*)&Gl[wp * 68 + w0];
          a1 += a * *(const f32x4*)&Gl[wp * 68 + w0 + 4];
          a2 += a * *(const f32x4*)&Gl[wp * 68 + w0 + 8];
          a3 += a * *(const f32x4*)&Gl[wp * 68 + w0 + 12];
        }
        *(f32x4*)&Bl[j * 68 + w0]      = a0;
        *(f32x4*)&Bl[j * 68 + w0 + 4]  = a1;
        *(f32x4*)&Bl[j * 68 + w0 + 8]  = a2;
        *(f32x4*)&Bl[j * 68 + w0 + 12] = a3;
      } else if (NP == 16) {
        const int j = tid >> 4, w0 = (tid & 15) * 4;
        f32x4 a0 = {0.f,0.f,0.f,0.f};
#pragma unroll 8
        for (int wp = 0; wp < 64; wp++)
          a0 += Al[j * 68 + wp] * *(const f32x4*)&Gl[wp * 68 + w0];
        *(f32x4*)&Bl[j * 68 + w0] = a0;
      } else {
        const int j = tid >> 6, w = tid & 63;
        float a0 = 0.f;
#pragma unroll 8
        for (int wp = 0; wp < 64; wp++) a0 += Al[j * 68 + wp] * Gl[wp * 68 + w];
        Bl[j * 68 + w] = a0;
      }
      __syncthreads();
      if (NP == 64) {
        const int j0 = (tid >> 4) * 4, jp = tid & 15;
#pragma unroll 4
        for (int w4 = 0; w4 < 16; w4++) {
          const f32x4 b0 = *(const f32x4*)&Bl[(j0 + 0) * 68 + w4 * 4];
          const f32x4 b1 = *(const f32x4*)&Bl[(j0 + 1) * 68 + w4 * 4];
          const f32x4 b2 = *(const f32x4*)&Bl[(j0 + 2) * 68 + w4 * 4];
          const f32x4 b3 = *(const f32x4*)&Bl[(j0 + 3) * 68 + w4 * 4];
#pragma unroll
          for (int bb = 0; bb < 4; bb++) {
            const f32x4 av = *(const f32x4*)&Al[(jp + 16 * bb) * 68 + w4 * 4];
            qq0[bb] += b0[0]*av[0] + b0[1]*av[1] + b0[2]*av[2] + b0[3]*av[3];
            qq1[bb] += b1[0]*av[0] + b1[1]*av[1] + b1[2]*av[2] + b1[3]*av[3];
            qq2[bb] += b2[0]*av[0] + b2[1]*av[1] + b2[2]*av[2] + b2[3]*av[3];
            qq3[bb] += b3[0]*av[0] + b3[1]*av[1] + b3[2]*av[2] + b3[3]*av[3];
          }
        }
      } else if (NP == 16) {
        const int j = tid >> 4, jp = tid & 15;
#pragma unroll 4
        for (int w4 = 0; w4 < 16; w4++) {
          const f32x4 bv = *(const f32x4*)&Bl[j * 68 + w4 * 4];
          const f32x4 av = *(const f32x4*)&Al[jp * 68 + w4 * 4];
          q1acc += bv[0]*av[0] + bv[1]*av[1] + bv[2]*av[2] + bv[3]*av[3];
        }
      } else {
        if (tid < 16) {
          const int j = tid >> 2, jp = tid & 3;
#pragma unroll 8
          for (int w = 0; w < 64; w++) q1acc += Bl[j * 68 + w] * Al[jp * 68 + w];
        }
      }
    }
    if (NP == 64) {
      const int j0 = (tid >> 4) * 4, jp = tid & 15;
#pragma unroll
      for (int bb = 0; bb < 4; bb++) {
        atomicAdd(&ws[qoff + (j0 + 0) * 64 + jp + 16 * bb], qq0[bb]);
        atomicAdd(&ws[qoff + (j0 + 1) * 64 + jp + 16 * bb], qq1[bb]);
        atomicAdd(&ws[qoff + (j0 + 2) * 64 + jp + 16 * bb], qq2[bb]);
        atomicAdd(&ws[qoff + (j0 + 3) * 64 + jp + 16 * bb], qq3[bb]);
      }
    } else if (NP == 16) {
      atomicAdd(&ws[qoff + (tid >> 4) * 16 + (tid & 15)], q1acc);
    } else if (tid < 16) {
      atomicAdd(&ws[qoff + tid], q1acc);
    }
  } else {
    const int vb = b - 164;
    const int lo = vb * 85, hi = (vb == 3) ? 340 : lo + 85;
    for (int vec = lo + it; vec < hi; vec += 4) {
      const float* mat; int dst;
      if (vec < 4)       { mat = Win + vec * 4096;                dst = OFF_SV1 + vec * 64; }
      else if (vec < 20) { mat = ws + OFF_P2 + (vec - 4) * 4096;  dst = OFF_SV2 + (vec - 4) * 64; }
      else if (vec < 84) { mat = ws + OFF_P3 + (vec - 20) * 4096; dst = OFF_SV3 + (vec - 20) * 64; }
      else               { mat = ws + OFF_P4 + (vec - 84) * 4096; dst = OFF_SV4 + (vec - 84) * 64; }
      float acc = 0.f;
#pragma unroll
      for (int u4 = 0; u4 < 16; u4++) {
        const f32x4 mv = *(const f32x4*)(mat + lane * 64 + u4 * 4);
        acc += mv[0]*sl[u4*4] + mv[1]*sl[u4*4+1] + mv[2]*sl[u4*4+2] + mv[3]*sl[u4*4+3];
      }
      ws[dst + lane] = acc;
    }
  }
}

// ---------- kLM: table-based ladder + Mo rows + n2 partials -----------------
__global__ __launch_bounds__(256) void kLM(
    const float* __restrict__ bin, const float* __restrict__ bout,
    float* __restrict__ ws) {
  __shared__ float binl[256], c2l[256], c3l[256], c4l[256], col[64];
  __shared__ float sv1l[256], sv2l[1024];
  __shared__ float inv1[4], inv2[4], inv3[4], inv4[4];
  __shared__ float C2l[4], C3l[16], C4l[64], mco[256];
  __shared__ __align__(16) float Grow[64 * 68];
  __shared__ float sl[64];
  __shared__ float tfl[4][64];
  __shared__ float redb[256];
  const int tid = threadIdx.x, it = tid >> 6, lane = tid & 63;

  binl[tid] = bin[tid];
  sv1l[tid] = ws[OFF_SV1 + tid];
#pragma unroll
  for (int m = 0; m < 4; m++) sv2l[m * 256 + tid] = ws[OFF_SV2 + m * 256 + tid];
  if (tid < 64) sl[tid] = ws[OFF_S + tid];
  ld64(Grow, ws + OFF_G, tid);
  __syncthreads();

  // rung 1
  {
    const float c = binl[it * 64 + lane];
    float part = c * (2.f * sv1l[it * 64 + lane] + BF * c);
#pragma unroll
    for (int off = 32; off; off >>= 1) part += __shfl_down(part, off, 64);
    if (lane == 0) inv1[it] = rsqrtf(ws[OFF_Q1 + it] + part);
  }
  __syncthreads();
  if (tid < 4) C2l[tid] = inv1[tid];
  __syncthreads();
  // c2[tgt=it] from tables: coalesced
  {
    float acc = ws[OFF_B0 + it * 64 + lane];
#pragma unroll
    for (int p1 = 0; p1 < 4; p1++)
      acc += inv1[p1] * ws[OFF_U2 + (p1 * 4 + it) * 64 + lane];
    c2l[it * 64 + lane] = acc;
  }
  __syncthreads();
  // rung 2
  {
    float ts = 0.f;
#pragma unroll
    for (int p1 = 0; p1 < 4; p1++) ts += C2l[p1] * sv2l[(p1 * 4 + it) * 64 + lane];
    const float c = c2l[it * 64 + lane];
    float part = c * (2.f * ts + BF * c);
    if (lane < 16) part += C2l[lane >> 2] * C2l[lane & 3] * ws[OFF_Q2 + it * 16 + lane];
#pragma unroll
    for (int off = 32; off; off >>= 1) part += __shfl_down(part, off, 64);
    if (lane == 0) inv2[it] = rsqrtf(part);
  }
  __syncthreads();
  if (tid < 16) C3l[tid] = C2l[tid >> 2] * inv2[tid & 3];
  __syncthreads();
  // c3[tgt=it] from tables
  {
    float acc = ws[OFF_B1 + it * 64 + lane];
#pragma unroll
    for (int p2 = 0; p2 < 4; p2++) {
      float tmp = ws[OFF_V3 + (p2 * 4 + it) * 64 + lane];
#pragma unroll
      for (int p1 = 0; p1 < 4; p1++)
        tmp += inv1[p1] * ws[OFF_U3 + ((p1 * 4 + p2) * 4 + it) * 64 + lane];
      acc += inv2[p2] * tmp;
    }
    c3l[it * 64 + lane] = acc;
  }
  __syncthreads();
  // rung 3
  {
    float ts = 0.f;
#pragma unroll
    for (int j = 0; j < 16; j++) ts += C3l[j] * ws[OFF_SV3 + (j * 4 + it) * 64 + lane];
    const float c = c3l[it * 64 + lane];
    float part = c * (2.f * ts + BF * c);
#pragma unroll
    for (int k = 0; k < 4; k++) {
      const int idx = lane * 4 + k;
      part += C3l[idx >> 4] * C3l[idx & 15] * ws[OFF_Q3 + it * 256 + idx];
    }
#pragma unroll
    for (int off = 32; off; off >>= 1) part += __shfl_down(part, off, 64);
    if (lane == 0) inv3[it] = rsqrtf(part);
  }
  __syncthreads();
  if (tid < 64) C4l[tid] = C3l[tid >> 2] * inv3[tid & 3];
  __syncthreads();
  // c4[tgt=it] from tables
  {
    float acc = ws[OFF_B2 + it * 64 + lane];
#pragma unroll
    for (int p3 = 0; p3 < 4; p3++) {
      float t3 = ws[OFF_V4B + (p3 * 4 + it) * 64 + lane];
#pragma unroll
      for (int p2 = 0; p2 < 4; p2++) {
        float t2 = ws[OFF_V4A + ((p2 * 4 + p3) * 4 + it) * 64 + lane];
#pragma unroll
        for (int p1 = 0; p1 < 4; p1++)
          t2 += inv1[p1] * ws[OFF_U4 + (((p1 * 4 + p2) * 4 + p3) * 4 + it) * 64 + lane];
        t3 += inv2[p2] * t2;
      }
      acc += inv3[p3] * t3;
    }
    c4l[it * 64 + lane] = acc;
  }
  __syncthreads();
  // rung 4 (coalesced Q4 column-sum form)
  {
    float ts = 0.f;
    for (int j = 0; j < 64; j++) ts += C4l[j] * ws[OFF_SV4 + (j * 4 + it) * 64 + lane];
    const float c = c4l[it * 64 + lane];
    float part = c * (2.f * ts + BF * c);
    float colv = 0.f;
#pragma unroll 8
    for (int j = 0; j < 64; j++)
      colv += C4l[j] * ws[OFF_Q4 + it * 4096 + j * 64 + lane];
    part += C4l[lane] * colv;
#pragma unroll
    for (int off = 32; off; off >>= 1) part += __shfl_down(part, off, 64);
    if (lane == 0) inv4[it] = rsqrtf(part);
  }
  __syncthreads();
  mco[tid] = C4l[tid >> 2] * inv4[tid & 3];
  // c_out partial from tables (c2l as scratch): wave p4 = it
  {
    float acc = ws[OFF_VOC + it * 64 + lane];
#pragma unroll
    for (int p3 = 0; p3 < 4; p3++) {
      float t3 = ws[OFF_VOB + (p3 * 4 + it) * 64 + lane];
#pragma unroll
      for (int p2 = 0; p2 < 4; p2++) {
        float t2 = ws[OFF_VOA + ((p2 * 4 + p3) * 4 + it) * 64 + lane];
#pragma unroll
        for (int p1 = 0; p1 < 4; p1++)
          t2 += inv1[p1] * ws[OFF_UO + (((p1 * 4 + p2) * 4 + p3) * 4 + it) * 64 + lane];
        t3 += inv2[p2] * t2;
      }
      acc += inv3[p3] * t3;
    }
    c2l[it * 64 + lane] = inv4[it] * acc + bout[it * 64 + lane];
  }
  __syncthreads();
  if (tid < 64) col[tid] = c2l[tid] + c2l[64 + tid] + c2l[128 + tid] + c2l[192 + tid];
  __syncthreads();
  if (blockIdx.x == 0 && tid < 64) ws[OFF_COUT + tid] = col[tid];

  // ---- M phase: form Mo rows v = blockIdx.x*4 + it ----
  const int v = blockIdx.x * 4 + it;
  {
    float acc = 0.f;
    const float* po = ws + OFF_PO + v * 64 + lane;
#pragma unroll 4
    for (int i = 0; i < 256; i++) acc += mco[i] * po[(long)i * 4096];
    tfl[it][lane] = acc;
    ws[OFF_MO + v * 64 + lane] = acc;
  }
  __syncthreads();
  // n2 partial
  {
    float bw = 0.f;
#pragma unroll 8
    for (int wp = 0; wp < 64; wp++) bw += tfl[it][wp] * Grow[wp * 68 + lane];
    float part = bw * tfl[it][lane] + 2.f * col[v] * tfl[it][lane] * sl[lane];
    redb[tid] = part;
    __syncthreads();
    for (int st = 128; st > 0; st >>= 1) {
      if (tid < st) redb[tid] += redb[tid + st];
      __syncthreads();
    }
    if (tid == 0) atomicAdd(&ws[OFF_N2], redb[0]);
    if (blockIdx.x == 0 && it == 0) {
      float p2_ = BF * col[lane] * col[lane];
#pragma unroll
      for (int off = 32; off; off >>= 1) p2_ += __shfl_down(p2_, off, 64);
      if (lane == 0) atomicAdd(&ws[OFF_N2], p2_);
    }
  }
}

// ---------- kApply: out = (x @ Mo^T + c_out) * rsqrt(n2) --------------------
__global__ __launch_bounds__(256) void kApply(const unsigned short* __restrict__ x16,
                                              const float* __restrict__ MoU,
                                              const float* __restrict__ coU,
                                              const float* __restrict__ n2p,
                                              float* __restrict__ out) {
  const int tid = threadIdx.x, lane = tid & 63, vt = tid >> 6;
  const int col = lane & 15, q = lane >> 4;
  const float inv = rsqrtf(n2p[0]);

  bf16x8 bfr[2];
  const float* mr = MoU + (vt * 16 + col) * 64 + q * 8;
  bfr[0] = cvt8(*(const f32x4*)mr, *(const f32x4*)(mr + 4), inv);
  bfr[1] = cvt8(*(const f32x4*)(mr + 32), *(const f32x4*)(mr + 36), inv);
  const float cf = inv * coU[vt * 16 + col];

  for (int t = 0; t < 16; t++) {
    const int b0 = (blockIdx.x * 16 + t) * 16;
    const unsigned short* xr = x16 + (long)(b0 + col) * 64 + q * 8;
    const bf16x8 a0 = *(const bf16x8*)xr;
    const bf16x8 a1 = *(const bf16x8*)(xr + 32);
    f32x4 acc = (f32x4){0.f, 0.f, 0.f, 0.f};
    acc = __builtin_amdgcn_mfma_f32_16x16x32_bf16(a0, bfr[0], acc, 0, 0, 0);
    acc = __builtin_amdgcn_mfma_f32_16x16x32_bf16(a1, bfr[1], acc, 0, 0, 0);
#pragma unroll
    for (int r = 0; r < 4; r++)
      out[(long)(b0 + q * 4 + r) * 64 + vt * 16 + col] = acc[r] + cf;
  }
}

extern "C" void kernel_launch(void* const* d_in, const int* in_sizes, int n_in,
                              void* d_out, int out_size, void* d_ws, size_t ws_size,
                              hipStream_t stream) {
  const float* x    = (const float*)d_in[0];
  const float* Win  = (const float*)d_in[1];
  const float* bin  = (const float*)d_in[2];
  const float* Wmid = (const float*)d_in[3];
  const float* bmid = (const float*)d_in[4];
  const float* Wout = (const float*)d_in[5];
  const float* bout = (const float*)d_in[6];
  float* out = (float*)d_out;
  float* ws  = (float*)d_ws;
  float* Gpart = out;   // 8.5 MB scratch inside d_out; fully overwritten by kApply
  unsigned short* x16 = (unsigned short*)(ws + OFF_X16);

  kGP  <<<768, 256, 0, stream>>>(x, Gpart, x16, Win, bin, Wmid, bmid, Wout, ws);
  kGred<<<65, 256, 0, stream>>>(Gpart, ws);
  kTab <<<168, 256, 0, stream>>>(Win, ws);
  kLM  <<<16, 256, 0, stream>>>(bin, bout, ws);
  kApply<<<1024, 256, 0, stream>>>(x16, ws + OFF_MO, ws + OFF_COUT, ws + OFF_N2, out);
}